// Round 1
// baseline (337.235 us; speedup 1.0000x reference)
//
#include <hip/hip_runtime.h>

// Problem constants (B,H,W,C) = (16,512,512,3), float32.
// B*H*W = 2^22 pixels per warp-op; 4 ops total.
#define BB 16
#define HH 512
#define WW 512
#define CC 3

__global__ __launch_bounds__(256) void warp4_kernel(
    const float* __restrict__ frame0, const float* __restrict__ frame1,
    const float* __restrict__ f01, const float* __restrict__ f10,
    const float* __restrict__ ft0, const float* __restrict__ ft1,
    float* __restrict__ out)
{
    // Each thread handles 4 consecutive pixels (never crosses a row: W=512 % 4 == 0).
    const unsigned long long tid  = (unsigned long long)blockIdx.x * blockDim.x + threadIdx.x;
    const unsigned long long pix4 = tid << 2;   // first of 4 pixels, flat over [op,b,y,x]

    const int x  = (int)( pix4        & (WW - 1));
    const int y  = (int)((pix4 >> 9)  & (HH - 1));
    const int b  = (int)((pix4 >> 18) & (BB - 1));
    const int op = (int)( pix4 >> 22);          // 0..3, block-uniform

    // op -> (image, flow):  0:(f1,f01) 1:(f0,f10) 2:(f0,ft0) 3:(f1,ft1)
    const float* img  = (op == 1 || op == 2) ? frame0 : frame1;
    const float* flow = (op == 0) ? f01 : (op == 1) ? f10 : (op == 2) ? ft0 : ft1;

    // Flow: [B,H,W,2]; offset is multiple of 8 floats -> 32B aligned float4 loads.
    const size_t pixInOp = ((size_t)b * HH + y) * WW + x;
    const float4 fl0 = *(const float4*)(flow + pixInOp * 2);
    const float4 fl1 = *(const float4*)(flow + pixInOp * 2 + 4);

    const float fly[4] = {fl0.x, fl0.z, fl1.x, fl1.z};   // flow[...,0] = dy
    const float flx[4] = {fl0.y, fl0.w, fl1.y, fl1.w};   // flow[...,1] = dx

    const float* imgb = img + (size_t)b * (HH * WW * CC);

    float res[12];
#pragma unroll
    for (int p = 0; p < 4; ++p) {
        const float qy = (float)y       - fly[p];
        const float qx = (float)(x + p) - flx[p];
        float fy = floorf(qy); fy = fminf(fmaxf(fy, 0.0f), (float)(HH - 2));
        float fx = floorf(qx); fx = fminf(fmaxf(fx, 0.0f), (float)(WW - 2));
        const float ay = fminf(fmaxf(qy - fy, 0.0f), 1.0f);
        const float ax = fminf(fmaxf(qx - fx, 0.0f), 1.0f);
        const int y0 = (int)fy;
        const int x0 = (int)fx;
        const float* tl = imgb + ((size_t)y0 * WW + x0) * CC;
        const float* bl = tl + WW * CC;
#pragma unroll
        for (int c = 0; c < 3; ++c) {
            const float vtl = tl[c], vtr = tl[c + 3];
            const float vbl = bl[c], vbr = bl[c + 3];
            const float top = vtl + ax * (vtr - vtl);
            const float bot = vbl + ax * (vbr - vbl);
            res[p * 3 + c] = top + ay * (bot - top);
        }
    }

    // Output: concat of 4 [B,H,W,C] tensors == pix4 * 3 floats == tid * 12.
    float* o = out + (size_t)tid * 12;
    *(float4*)(o + 0) = make_float4(res[0], res[1], res[2],  res[3]);
    *(float4*)(o + 4) = make_float4(res[4], res[5], res[6],  res[7]);
    *(float4*)(o + 8) = make_float4(res[8], res[9], res[10], res[11]);
}

extern "C" void kernel_launch(void* const* d_in, const int* in_sizes, int n_in,
                              void* d_out, int out_size, void* d_ws, size_t ws_size,
                              hipStream_t stream) {
    const float* frame0 = (const float*)d_in[0];
    const float* frame1 = (const float*)d_in[1];
    const float* f01    = (const float*)d_in[2];
    const float* f10    = (const float*)d_in[3];
    const float* ft0    = (const float*)d_in[4];
    const float* ft1    = (const float*)d_in[5];
    float* out = (float*)d_out;

    // 4 ops * 2^22 pixels / 4 pixels-per-thread = 2^22 threads
    const int threads = 256;
    const int blocks  = (4u << 22) / 4 / threads;   // 16384
    hipLaunchKernelGGL(warp4_kernel, dim3(blocks), dim3(threads), 0, stream,
                       frame0, frame1, f01, f10, ft0, ft1, out);
}

// Round 3
// 171.589 us; speedup vs baseline: 1.9654x; 1.9654x over previous
//
#include <hip/hip_runtime.h>

// (B,H,W,C) = (16,512,512,3) float32. 4 warp ops.
// out concat order: 0:(frame1,f01) 1:(frame0,f10) 2:(frame0,ft0) 3:(frame1,ft1)
#define HH 512
#define WW 512
#define NPIX (16 * HH * WW)  // 4194304 pixels per op

// Native clang vector types (work with __builtin_nontemporal_*).
typedef float fv4 __attribute__((ext_vector_type(4)));
typedef float fv2 __attribute__((ext_vector_type(2)));

// 4B-aligned vector loads for the 6-float gather spans (x0 is arbitrary).
typedef fv4 fv4u __attribute__((aligned(4)));
typedef fv2 fv2u __attribute__((aligned(4)));

__device__ __forceinline__ void bilerp3(const float* __restrict__ imgb,
                                        float qy, float qx, float* __restrict__ r)
{
    float fy = floorf(qy); fy = fminf(fmaxf(fy, 0.0f), (float)(HH - 2));
    float fx = floorf(qx); fx = fminf(fmaxf(fx, 0.0f), (float)(WW - 2));
    const float ay = fminf(fmaxf(qy - fy, 0.0f), 1.0f);
    const float ax = fminf(fmaxf(qx - fx, 0.0f), 1.0f);
    const int y0 = (int)fy, x0 = (int)fx;
    const float* t  = imgb + ((size_t)y0 * WW + x0) * 3;
    const float* bo = t + WW * 3;
    const fv4u t4 = *(const fv4u*)t;  const fv2u t2 = *(const fv2u*)(t + 4);
    const fv4u b4 = *(const fv4u*)bo; const fv2u b2 = *(const fv2u*)(bo + 4);
    const float tv[6] = {t4.x, t4.y, t4.z, t4.w, t2.x, t2.y};
    const float bv[6] = {b4.x, b4.y, b4.z, b4.w, b2.x, b2.y};
#pragma unroll
    for (int c = 0; c < 3; ++c) {
        const float top = tv[c] + ax * (tv[c + 3] - tv[c]);
        const float bot = bv[c] + ax * (bv[c + 3] - bv[c]);
        r[c] = top + ay * (bot - top);
    }
}

// Block = 256 threads -> one 64x16 pixel tile of one (frame-group, b) image,
// computing BOTH ops that gather from that frame (frame tile reused in cache).
__global__ __launch_bounds__(256) void warp_pair_kernel(
    const float* __restrict__ frame0, const float* __restrict__ frame1,
    const float* __restrict__ f01, const float* __restrict__ f10,
    const float* __restrict__ ft0, const float* __restrict__ ft1,
    float* __restrict__ out)
{
    // 8192 blocks total. Bijective XCD chunking: XCD k gets a contiguous
    // 1024-block chunk (= 4 whole images; 3 MB frame image fits 4 MB L2).
    const unsigned bid = blockIdx.x;
    const unsigned v   = (bid & 7u) * 1024u + (bid >> 3);

    const unsigned tile  = v & 255u;        // 256 tiles per image
    const unsigned img_b = v >> 8;          // 0..31
    const int b  = (int)(img_b & 15u);
    const int fg = (int)(img_b >> 4);       // 0: frame0 ops{1,2}, 1: frame1 ops{0,3}

    const int tx = (int)(tile & 7u);        // 8 tiles of 64px in x
    const int ty = (int)(tile >> 3);        // 32 tiles of 16px in y
    const int lx = (int)(threadIdx.x & 15u);
    const int ly = (int)(threadIdx.x >> 4);
    const int x  = tx * 64 + lx * 4;        // 4 consecutive px per thread
    const int y  = ty * 16 + ly;

    const float* img   = fg ? frame1 : frame0;
    const float* flowA = fg ? f01 : f10;
    const float* flowB = fg ? ft1 : ft0;
    const size_t opA   = fg ? 0 : 1;
    const size_t opB   = fg ? 3 : 2;

    const size_t pixIn = ((size_t)b * HH + y) * WW + x;
    const float* imgb  = img + (size_t)b * (HH * WW * 3);

    // Flow loads: 32B-aligned fv4 pairs, nontemporal (streamed once).
    const fv4 a0 = __builtin_nontemporal_load((const fv4*)(flowA + pixIn * 2));
    const fv4 a1 = __builtin_nontemporal_load((const fv4*)(flowA + pixIn * 2) + 1);
    const fv4 c0 = __builtin_nontemporal_load((const fv4*)(flowB + pixIn * 2));
    const fv4 c1 = __builtin_nontemporal_load((const fv4*)(flowB + pixIn * 2) + 1);

    const float flyA[4] = {a0.x, a0.z, a1.x, a1.z};
    const float flxA[4] = {a0.y, a0.w, a1.y, a1.w};
    const float flyB[4] = {c0.x, c0.z, c1.x, c1.z};
    const float flxB[4] = {c0.y, c0.w, c1.y, c1.w};

    float resA[12], resB[12];
#pragma unroll
    for (int p = 0; p < 4; ++p) {
        bilerp3(imgb, (float)y - flyA[p], (float)(x + p) - flxA[p], resA + p * 3);
        bilerp3(imgb, (float)y - flyB[p], (float)(x + p) - flxB[p], resB + p * 3);
    }

    // Output: op-major concat; 16B-aligned (pixIn multiple of 4 -> *3 mult of 12).
    float* oA = out + (opA * NPIX + pixIn) * 3;
    float* oB = out + (opB * NPIX + pixIn) * 3;
    fv4 vA0 = {resA[0], resA[1], resA[2],  resA[3]};
    fv4 vA1 = {resA[4], resA[5], resA[6],  resA[7]};
    fv4 vA2 = {resA[8], resA[9], resA[10], resA[11]};
    fv4 vB0 = {resB[0], resB[1], resB[2],  resB[3]};
    fv4 vB1 = {resB[4], resB[5], resB[6],  resB[7]};
    fv4 vB2 = {resB[8], resB[9], resB[10], resB[11]};
    __builtin_nontemporal_store(vA0, (fv4*)oA);
    __builtin_nontemporal_store(vA1, (fv4*)oA + 1);
    __builtin_nontemporal_store(vA2, (fv4*)oA + 2);
    __builtin_nontemporal_store(vB0, (fv4*)oB);
    __builtin_nontemporal_store(vB1, (fv4*)oB + 1);
    __builtin_nontemporal_store(vB2, (fv4*)oB + 2);
}

extern "C" void kernel_launch(void* const* d_in, const int* in_sizes, int n_in,
                              void* d_out, int out_size, void* d_ws, size_t ws_size,
                              hipStream_t stream) {
    const float* frame0 = (const float*)d_in[0];
    const float* frame1 = (const float*)d_in[1];
    const float* f01    = (const float*)d_in[2];
    const float* f10    = (const float*)d_in[3];
    const float* ft0    = (const float*)d_in[4];
    const float* ft1    = (const float*)d_in[5];
    float* out = (float*)d_out;

    // 2 frame-groups * 16 b * 256 tiles = 8192 blocks of 256 threads.
    hipLaunchKernelGGL(warp_pair_kernel, dim3(8192), dim3(256), 0, stream,
                       frame0, frame1, f01, f10, ft0, ft1, out);
}

// Round 4
// 162.877 us; speedup vs baseline: 2.0705x; 1.0535x over previous
//
#include <hip/hip_runtime.h>

// (B,H,W,C) = (16,512,512,3) float32. 4 warp ops.
// out concat order: 0:(frame1,f01) 1:(frame0,f10) 2:(frame0,ft0) 3:(frame1,ft1)
#define HH 512
#define WW 512
#define NPIX (16 * HH * WW)

#define TS    32                 // output tile edge
#define APR   16                 // apron (covers |flow| <= 16)
#define LW    (TS + 2 * APR)     // 64: staged region edge
#define LSTR  65                 // padded LDS row stride (dwords) -> bank=(y+x)%32
#define PLANE (LW * LSTR)        // 4160 dwords per channel plane

typedef float fv4 __attribute__((ext_vector_type(4)));
typedef float fv2 __attribute__((ext_vector_type(2)));
typedef fv4 fv4u __attribute__((aligned(4)));
typedef fv2 fv2u __attribute__((aligned(4)));

__device__ __forceinline__ void sample(const float* __restrict__ imgb,
                                       const float* __restrict__ s,
                                       int AX0, int AY0,
                                       float qy, float qx, float* __restrict__ r)
{
    float fy = floorf(qy); fy = fminf(fmaxf(fy, 0.0f), (float)(HH - 2));
    float fx = floorf(qx); fx = fminf(fmaxf(fx, 0.0f), (float)(WW - 2));
    const float ay = fminf(fmaxf(qy - fy, 0.0f), 1.0f);
    const float ax = fminf(fmaxf(qx - fx, 0.0f), 1.0f);
    const int y0 = (int)fy, x0 = (int)fx;
    const int yl = y0 - AY0, xl = x0 - AX0;
    if ((unsigned)yl < (unsigned)(LW - 1) && (unsigned)xl < (unsigned)(LW - 1)) {
        // LDS path: per channel, ds_read2-friendly adjacent pairs
        const float* t = s + yl * LSTR + xl;
#pragma unroll
        for (int c = 0; c < 3; ++c) {
            const float* pc = t + c * PLANE;
            const float tl = pc[0], tr = pc[1], bl = pc[LSTR], br = pc[LSTR + 1];
            const float top = tl + ax * (tr - tl);
            const float bot = bl + ax * (br - bl);
            r[c] = top + ay * (bot - top);
        }
    } else {
        // rare global fallback (|flow| > apron): exact same math
        const float* t  = imgb + ((size_t)y0 * WW + x0) * 3;
        const float* bo = t + WW * 3;
        const fv4u t4 = *(const fv4u*)t;  const fv2u t2 = *(const fv2u*)(t + 4);
        const fv4u b4 = *(const fv4u*)bo; const fv2u b2 = *(const fv2u*)(bo + 4);
        const float tv[6] = {t4.x, t4.y, t4.z, t4.w, t2.x, t2.y};
        const float bv[6] = {b4.x, b4.y, b4.z, b4.w, b2.x, b2.y};
#pragma unroll
        for (int c = 0; c < 3; ++c) {
            const float top = tv[c] + ax * (tv[c + 3] - tv[c]);
            const float bot = bv[c] + ax * (bv[c + 3] - bv[c]);
            r[c] = top + ay * (bot - top);
        }
    }
}

__global__ __launch_bounds__(256) void warp_tile_kernel(
    const float* __restrict__ frame0, const float* __restrict__ frame1,
    const float* __restrict__ f01, const float* __restrict__ f10,
    const float* __restrict__ ft0, const float* __restrict__ ft1,
    float* __restrict__ out)
{
    __shared__ float lds[3 * PLANE];   // 49,920 B -> 3 blocks/CU

    // 8192 blocks; bijective XCD chunking: each XCD gets 1024 contiguous units
    // (= 4 whole (fg,b) images; 3 MB image fits 4 MB per-XCD L2).
    const unsigned bid = blockIdx.x;
    const unsigned v   = (bid & 7u) * 1024u + (bid >> 3);

    const unsigned tile  = v & 255u;   // 16x16 tiles per image
    const unsigned img_b = v >> 8;     // 0..31
    const int b  = (int)(img_b & 15u);
    const int fg = (int)(img_b >> 4);  // 0: frame0 ops{1,2}, 1: frame1 ops{0,3}

    const int tx = (int)(tile & 15u);
    const int ty = (int)(tile >> 4);
    const int X0 = tx * TS, Y0 = ty * TS;
    const int AX0 = X0 - APR, AY0 = Y0 - APR;

    const float* img   = fg ? frame1 : frame0;
    const float* flowA = fg ? f01 : f10;
    const float* flowB = fg ? ft1 : ft0;
    const size_t opA   = fg ? 0 : 1;
    const size_t opB   = fg ? 3 : 2;

    const float* imgb = img + (size_t)b * (HH * WW * 3);

    const int tid = (int)threadIdx.x;
    const int lx = (tid & 7) * 4;      // 8 threads x 4 px cover 32 px row
    const int ly = tid >> 3;           // 32 rows
    const int x = X0 + lx, y = Y0 + ly;
    const size_t pixIn = ((size_t)b * HH + y) * WW + x;

    // Issue flow loads early; they overlap the staging phase.
    const fv4 a0 = __builtin_nontemporal_load((const fv4*)(flowA + pixIn * 2));
    const fv4 a1 = __builtin_nontemporal_load((const fv4*)(flowA + pixIn * 2) + 1);
    const fv4 c0 = __builtin_nontemporal_load((const fv4*)(flowB + pixIn * 2));
    const fv4 c1 = __builtin_nontemporal_load((const fv4*)(flowB + pixIn * 2) + 1);

    // ---- Stage 64x64x3 apron region into LDS (SoA planes, row stride 65).
    // Global-linear dword order for coalescing: d = (k*256+tid)*4 in [0,12288).
    {
        int d   = tid * 4;
        int row = d / 192;             // 192 dwords per region row (64 px * 3ch)
        int rd  = d % 192;
#pragma unroll
        for (int k = 0; k < 12; ++k) {
            const int gy = min(max(AY0 + row, 0), HH - 1);
            const float* rowp = imgb + (size_t)gy * (WW * 3) + (ptrdiff_t)AX0 * 3;
            const int p0 = rd / 3;
            const int r0 = rd - p0 * 3;
            const int pmin = AX0 + p0;          // 4 dwords span exactly px p0..p0+1
            const int pmax = pmin + 1;
            float vals[4];
            if (pmin >= 0 && pmax <= WW - 1) {
                const fv4 t = *(const fv4*)(rowp + rd);   // 16B aligned
                vals[0] = t.x; vals[1] = t.y; vals[2] = t.z; vals[3] = t.w;
            } else {
                // edge tiles: per-element clamped gather (x clamp only)
#pragma unroll
                for (int j = 0; j < 4; ++j) {
                    const int e  = rd + j;
                    const int pe = e / 3;
                    const int ce = e - pe * 3;
                    const int gx = min(max(AX0 + pe, 0), WW - 1);
                    vals[j] = imgb[((size_t)gy * WW + gx) * 3 + ce];
                }
            }
            int p = p0, c = r0;
#pragma unroll
            for (int j = 0; j < 4; ++j) {
                lds[c * PLANE + row * LSTR + p] = vals[j];
                ++c; if (c == 3) { c = 0; ++p; }
            }
            // advance by 1024 dwords: 1024 = 5*192 + 64
            rd += 64; row += 5;
            if (rd >= 192) { rd -= 192; row += 1; }
        }
    }
    __syncthreads();

    const float flyA[4] = {a0.x, a0.z, a1.x, a1.z};
    const float flxA[4] = {a0.y, a0.w, a1.y, a1.w};
    const float flyB[4] = {c0.x, c0.z, c1.x, c1.z};
    const float flxB[4] = {c0.y, c0.w, c1.y, c1.w};

    float resA[12], resB[12];
#pragma unroll
    for (int p = 0; p < 4; ++p) {
        sample(imgb, lds, AX0, AY0, (float)y - flyA[p], (float)(x + p) - flxA[p], resA + 3 * p);
        sample(imgb, lds, AX0, AY0, (float)y - flyB[p], (float)(x + p) - flxB[p], resB + 3 * p);
    }

    float* oA = out + (opA * NPIX + pixIn) * 3;
    float* oB = out + (opB * NPIX + pixIn) * 3;
    fv4 vA0 = {resA[0], resA[1], resA[2],  resA[3]};
    fv4 vA1 = {resA[4], resA[5], resA[6],  resA[7]};
    fv4 vA2 = {resA[8], resA[9], resA[10], resA[11]};
    fv4 vB0 = {resB[0], resB[1], resB[2],  resB[3]};
    fv4 vB1 = {resB[4], resB[5], resB[6],  resB[7]};
    fv4 vB2 = {resB[8], resB[9], resB[10], resB[11]};
    __builtin_nontemporal_store(vA0, (fv4*)oA);
    __builtin_nontemporal_store(vA1, (fv4*)oA + 1);
    __builtin_nontemporal_store(vA2, (fv4*)oA + 2);
    __builtin_nontemporal_store(vB0, (fv4*)oB);
    __builtin_nontemporal_store(vB1, (fv4*)oB + 1);
    __builtin_nontemporal_store(vB2, (fv4*)oB + 2);
}

extern "C" void kernel_launch(void* const* d_in, const int* in_sizes, int n_in,
                              void* d_out, int out_size, void* d_ws, size_t ws_size,
                              hipStream_t stream) {
    const float* frame0 = (const float*)d_in[0];
    const float* frame1 = (const float*)d_in[1];
    const float* f01    = (const float*)d_in[2];
    const float* f10    = (const float*)d_in[3];
    const float* ft0    = (const float*)d_in[4];
    const float* ft1    = (const float*)d_in[5];
    float* out = (float*)d_out;

    // 2 frame-groups * 16 b * 256 tiles = 8192 blocks of 256 threads.
    hipLaunchKernelGGL(warp_tile_kernel, dim3(8192), dim3(256), 0, stream,
                       frame0, frame1, f01, f10, ft0, ft1, out);
}

// Round 5
// 141.327 us; speedup vs baseline: 2.3862x; 1.1525x over previous
//
#include <hip/hip_runtime.h>

// (B,H,W,C) = (16,512,512,3) float32. 4 warp ops.
// out concat order: 0:(frame1,f01) 1:(frame0,f10) 2:(frame0,ft0) 3:(frame1,ft1)
#define HH 512
#define WW 512
#define NPIX (16 * HH * WW)
#define ROWD_G (WW * 3)          // global image row stride in dwords

#define TS    32                 // output tile edge
#define APR   12                 // apron (covers |flow| <= 12 worst-case at tile edge)
#define LW    (TS + 2 * APR)     // 56: staged region edge
#define ROWD  (LW * 3)           // 168 dwords of payload per region row
#define LSTR  172                // padded row stride in dwords (16B-aligned, %32=12)
#define NDW   (LW * ROWD)        // 9408 staged dwords

typedef float fv4 __attribute__((ext_vector_type(4)));
typedef float fv2 __attribute__((ext_vector_type(2)));
typedef fv4 fv4u __attribute__((aligned(4)));
typedef fv2 fv2u __attribute__((aligned(4)));

__device__ __forceinline__ void sample(const float* __restrict__ imgb,
                                       const float* __restrict__ s,
                                       int AX0, int AY0,
                                       float qy, float qx, float* __restrict__ r)
{
    float fy = floorf(qy); fy = fminf(fmaxf(fy, 0.0f), (float)(HH - 2));
    float fx = floorf(qx); fx = fminf(fmaxf(fx, 0.0f), (float)(WW - 2));
    const float ay = fminf(fmaxf(qy - fy, 0.0f), 1.0f);
    const float ax = fminf(fmaxf(qx - fx, 0.0f), 1.0f);
    const int y0 = (int)fy, x0 = (int)fx;
    const int yl = y0 - AY0, xl = x0 - AX0;
    if ((unsigned)yl < (unsigned)(LW - 1) && (unsigned)xl < (unsigned)(LW - 1)) {
        // LDS path: AoS rows; 6 contiguous dwords per row -> ds_read2_b32 x3
        const float* t  = s + yl * LSTR + 3 * xl;
        const float* bo = t + LSTR;
#pragma unroll
        for (int c = 0; c < 3; ++c) {
            const float tl = t[c],  tr = t[c + 3];
            const float bl = bo[c], br = bo[c + 3];
            const float top = tl + ax * (tr - tl);
            const float bot = bl + ax * (br - bl);
            r[c] = top + ay * (bot - top);
        }
    } else {
        // rare global fallback (|flow| beyond apron): exact same math
        const float* t  = imgb + ((size_t)y0 * WW + x0) * 3;
        const float* bo = t + WW * 3;
        const fv4u t4 = *(const fv4u*)t;  const fv2u t2 = *(const fv2u*)(t + 4);
        const fv4u b4 = *(const fv4u*)bo; const fv2u b2 = *(const fv2u*)(bo + 4);
        const float tv[6] = {t4.x, t4.y, t4.z, t4.w, t2.x, t2.y};
        const float bv[6] = {b4.x, b4.y, b4.z, b4.w, b2.x, b2.y};
#pragma unroll
        for (int c = 0; c < 3; ++c) {
            const float top = tv[c] + ax * (tv[c + 3] - tv[c]);
            const float bot = bv[c] + ax * (bv[c + 3] - bv[c]);
            r[c] = top + ay * (bot - top);
        }
    }
}

__global__ __launch_bounds__(256) void warp_tile_kernel(
    const float* __restrict__ frame0, const float* __restrict__ frame1,
    const float* __restrict__ f01, const float* __restrict__ f10,
    const float* __restrict__ ft0, const float* __restrict__ ft1,
    float* __restrict__ out)
{
    __shared__ float lds[LW * LSTR];   // 56*172*4 = 38,528 B -> 4 blocks/CU

    // 8192 blocks; bijective XCD chunking: each XCD gets 1024 contiguous units
    // (= 4 whole (fg,b) images; 3 MB image fits 4 MB per-XCD L2).
    const unsigned bid = blockIdx.x;
    const unsigned v   = (bid & 7u) * 1024u + (bid >> 3);

    const unsigned tile  = v & 255u;   // 16x16 tiles per image
    const unsigned img_b = v >> 8;     // 0..31
    const int b  = (int)(img_b & 15u);
    const int fg = (int)(img_b >> 4);  // 0: frame0 ops{1,2}, 1: frame1 ops{0,3}

    const int tx = (int)(tile & 15u);
    const int ty = (int)(tile >> 4);
    const int X0 = tx * TS, Y0 = ty * TS;
    const int AX0 = X0 - APR, AY0 = Y0 - APR;

    const float* img   = fg ? frame1 : frame0;
    const float* flowA = fg ? f01 : f10;
    const float* flowB = fg ? ft1 : ft0;
    const size_t opA   = fg ? 0 : 1;
    const size_t opB   = fg ? 3 : 2;

    const float* imgb = img + (size_t)b * (HH * WW * 3);

    const int tid = (int)threadIdx.x;
    const int lx = (tid & 7) * 4;      // 8 threads x 4 px cover 32 px row
    const int ly = tid >> 3;           // 32 rows
    const int x = X0 + lx, y = Y0 + ly;
    const size_t pixIn = ((size_t)b * HH + y) * WW + x;

    // Issue flow loads early; they overlap the staging phase.
    const fv4 a0 = __builtin_nontemporal_load((const fv4*)(flowA + pixIn * 2));
    const fv4 a1 = __builtin_nontemporal_load((const fv4*)(flowA + pixIn * 2) + 1);
    const fv4 c0 = __builtin_nontemporal_load((const fv4*)(flowB + pixIn * 2));
    const fv4 c1 = __builtin_nontemporal_load((const fv4*)(flowB + pixIn * 2) + 1);

    // ---- Stage 56x56 px apron region into LDS, AoS rows (stride 172 dwords).
    // Global-linear dword order: d = tid*4 + k*1024 over [0, 9408).
#pragma unroll
    for (int k = 0; k < 10; ++k) {
        const int d = tid * 4 + k * 1024;
        if (d < NDW) {
            const int row = d / ROWD;          // compile-time magic mul
            const int rd  = d - row * ROWD;    // multiple of 4; chunk stays in row
            const int gy  = min(max(AY0 + row, 0), HH - 1);
            const int p0  = rd / 3;            // chunk spans pixels p0, p0+1
            fv4 vals;
            if (AX0 + p0 >= 0 && AX0 + p0 + 1 <= WW - 1) {
                vals = *(const fv4*)(imgb + (size_t)gy * ROWD_G + (ptrdiff_t)AX0 * 3 + rd);
            } else {
#pragma unroll
                for (int j = 0; j < 4; ++j) {
                    const int e  = rd + j;
                    const int pe = e / 3;
                    const int ce = e - pe * 3;
                    const int gx = min(max(AX0 + pe, 0), WW - 1);
                    vals[j] = imgb[((size_t)gy * WW + gx) * 3 + ce];
                }
            }
            *(fv4*)(lds + row * LSTR + rd) = vals;   // ds_write_b128, conflict-free
        }
    }
    __syncthreads();

    const float flyA[4] = {a0.x, a0.z, a1.x, a1.z};
    const float flxA[4] = {a0.y, a0.w, a1.y, a1.w};
    const float flyB[4] = {c0.x, c0.z, c1.x, c1.z};
    const float flxB[4] = {c0.y, c0.w, c1.y, c1.w};

    float resA[12], resB[12];
#pragma unroll
    for (int p = 0; p < 4; ++p) {
        sample(imgb, lds, AX0, AY0, (float)y - flyA[p], (float)(x + p) - flxA[p], resA + 3 * p);
        sample(imgb, lds, AX0, AY0, (float)y - flyB[p], (float)(x + p) - flxB[p], resB + 3 * p);
    }

    float* oA = out + (opA * NPIX + pixIn) * 3;
    float* oB = out + (opB * NPIX + pixIn) * 3;
    fv4 vA0 = {resA[0], resA[1], resA[2],  resA[3]};
    fv4 vA1 = {resA[4], resA[5], resA[6],  resA[7]};
    fv4 vA2 = {resA[8], resA[9], resA[10], resA[11]};
    fv4 vB0 = {resB[0], resB[1], resB[2],  resB[3]};
    fv4 vB1 = {resB[4], resB[5], resB[6],  resB[7]};
    fv4 vB2 = {resB[8], resB[9], resB[10], resB[11]};
    __builtin_nontemporal_store(vA0, (fv4*)oA);
    __builtin_nontemporal_store(vA1, (fv4*)oA + 1);
    __builtin_nontemporal_store(vA2, (fv4*)oA + 2);
    __builtin_nontemporal_store(vB0, (fv4*)oB);
    __builtin_nontemporal_store(vB1, (fv4*)oB + 1);
    __builtin_nontemporal_store(vB2, (fv4*)oB + 2);
}

extern "C" void kernel_launch(void* const* d_in, const int* in_sizes, int n_in,
                              void* d_out, int out_size, void* d_ws, size_t ws_size,
                              hipStream_t stream) {
    const float* frame0 = (const float*)d_in[0];
    const float* frame1 = (const float*)d_in[1];
    const float* f01    = (const float*)d_in[2];
    const float* f10    = (const float*)d_in[3];
    const float* ft0    = (const float*)d_in[4];
    const float* ft1    = (const float*)d_in[5];
    float* out = (float*)d_out;

    // 2 frame-groups * 16 b * 256 tiles = 8192 blocks of 256 threads.
    hipLaunchKernelGGL(warp_tile_kernel, dim3(8192), dim3(256), 0, stream,
                       frame0, frame1, f01, f10, ft0, ft1, out);
}